// Round 8
// baseline (70.445 us; speedup 1.0000x reference)
//
#include <hip/hip_runtime.h>
#include <stdint.h>

// Problem constants
constexpr int NA  = 10000;   // atoms
constexpr int NH  = 75;      // hidden
constexpr int NPF = 14;      // pair features
constexpr int NW  = 5625;    // 75*75
constexpr int KK  = 1125;    // 15*75 contraction dim (f=0..13 W, f=14 bias)
constexpr int KK2 = 1152;    // padded to 36 MFMA k-steps
constexpr int HP  = 80;      // h padded to 5 n-frags
constexpr int MR2 = 10048;   // M rows padded to 628*16
constexpr int NKS = KK2 / 32;// 36

typedef _Float16 f16;
typedef __attribute__((ext_vector_type(8))) _Float16 f16x8;
typedef __attribute__((ext_vector_type(4))) float floatx4;

__device__ __forceinline__ ushort f2h_bits(float f) {
    return __builtin_bit_cast(ushort, (f16)f);       // v_cvt_f16_f32, RNE
}

// ---------- K1: prep = build Wth | zero M tail rows | rowstart(a0) ----------
// Wth[h][kk] f16, kk = f*75+k: f<14 -> W[f][h*75+k], f==14 -> bias[h*75+k], pad 0.
__global__ __launch_bounds__(256) void k_prep(
    const float* __restrict__ W, const float* __restrict__ bias,
    const int* __restrict__ atp,
    ushort* __restrict__ wth, ushort* __restrict__ M, int* __restrict__ rs,
    int E, int bWt, int bMz)
{
    const int b = blockIdx.x, tid = threadIdx.x;
    if (b < bWt) {
        int idx = b * 256 + tid;                 // quads over [HP][KK2/4]
        if (idx >= HP * (KK2 / 4)) return;
        int h = idx / (KK2 / 4), q = idx - h * (KK2 / 4);
        int kk0 = q * 4;
        ushort4 st = {0, 0, 0, 0};
        if (h < NH) {
            float v[4] = {0.f, 0.f, 0.f, 0.f};
            #pragma unroll
            for (int j = 0; j < 4; ++j) {
                int kk = kk0 + j;
                if (kk < KK) {
                    int f = kk / 75, k = kk - f * 75;
                    v[j] = (f < NPF) ? W[f * NW + h * 75 + k] : bias[h * 75 + k];
                }
            }
            st.x = f2h_bits(v[0]); st.y = f2h_bits(v[1]);
            st.z = f2h_bits(v[2]); st.w = f2h_bits(v[3]);
        }
        ((ushort4*)wth)[idx] = st;
    } else if (b < bWt + bMz) {
        // zero-fill M rows [NA, MR2) so GEMM tail reads are clean
        int idx = (b - bWt) * 256 + tid;         // quads
        int total = (MR2 - NA) * (KK2 / 4);      // 13824
        if (idx < total) {
            ushort4 z = {0, 0, 0, 0};
            ((ushort4*)(M + (size_t)NA * KK2))[idx] = z;
        }
    } else {
        // rowstart CSR from sorted atom_to_pair[:,0]
        int e = (b - bWt - bMz) * 256 + tid;
        if (e >= E) return;
        int c  = atp[2 * e];
        int cp = (e == 0) ? -1 : atp[2 * (e - 1)];
        for (int a = cp + 1; a <= c; ++a) rs[a] = e;
        if (e == E - 1)
            for (int a = c + 1; a <= NA; ++a) rs[a] = E;
    }
}

// ---------- K2: phase A — M[a0][f*75+k] = sum_{e in a0} pf[e,f]*af[a1(e),k] ----------
// One wave per atom (4 waves/block). Lane owns k = lane and k = 64+lane (lane<11).
// pf/atp reads are wave-uniform -> scalar loads; af reads coalesced gathers.
__global__ __launch_bounds__(256) void k_phaseA(
    const float* __restrict__ af, const float* __restrict__ pf,
    const int* __restrict__ atp, const int* __restrict__ rs,
    ushort* __restrict__ M)
{
    const int wid = threadIdx.x >> 6, lane = threadIdx.x & 63;
    const int a = blockIdx.x * 4 + wid;          // 2500*4 = 10000 exactly
    const int e0 = rs[a], e1 = rs[a + 1];

    float mac[15][2] = {};
    for (int e = e0; e < e1; ++e) {
        int a1 = atp[2 * e + 1];
        float av0 = af[a1 * NH + lane];
        float av1 = (lane < 11) ? af[a1 * NH + 64 + lane] : 0.f;
        float p[14];
        #pragma unroll
        for (int f = 0; f < 7; ++f) {
            float2 t = *(const float2*)&pf[(size_t)e * NPF + 2 * f];
            p[2 * f] = t.x; p[2 * f + 1] = t.y;
        }
        #pragma unroll
        for (int f = 0; f < 14; ++f) {
            mac[f][0] += p[f] * av0;
            mac[f][1] += p[f] * av1;
        }
        mac[14][0] += av0;                       // bias slot (pf == 1)
        mac[14][1] += av1;
    }

    ushort* mr = M + (size_t)a * KK2;
    #pragma unroll
    for (int f = 0; f < 15; ++f) {
        mr[f * 75 + lane] = f2h_bits(mac[f][0]);
        if (lane < 11) mr[f * 75 + 64 + lane] = f2h_bits(mac[f][1]);
    }
    if (lane < KK2 - KK) mr[KK + lane] = 0;      // 27 pad cols
}

// ---------- K3: out[a][h] = sum_kk M[a][kk] * Wth[h][kk]  (MFMA, M read once) ----------
// 1 wave per 16 a-rows; 5 n-frags cover h=0..79; no LDS, register pipelined.
// mfma(wth_frag, m_frag): D col (lane&15) = a-row, reg-axis = 4 consecutive h.
__global__ __launch_bounds__(64) void k_gemm2(
    const ushort* __restrict__ M, const ushort* __restrict__ wth,
    float* __restrict__ out)
{
    const int lane = threadIdx.x & 63;
    const int a0 = blockIdx.x * 16;
    const int lr = lane & 15, hi = lane >> 4;
    const int lk = hi * 8;

    floatx4 acc[5] = {};
    const ushort* mrow = M + (size_t)(a0 + lr) * KK2;

    #pragma unroll 4
    for (int ks = 0; ks < NKS; ++ks) {
        f16x8 mfr = *(const f16x8*)&mrow[ks * 32 + lk];
        #pragma unroll
        for (int nf = 0; nf < 5; ++nf) {
            f16x8 wfr = *(const f16x8*)&wth[(size_t)(nf * 16 + lr) * KK2 + ks * 32 + lk];
            acc[nf] = __builtin_amdgcn_mfma_f32_16x16x32_f16(wfr, mfr, acc[nf], 0, 0, 0);
        }
    }

    const int arow = a0 + lr;
    if (arow < NA) {
        #pragma unroll
        for (int nf = 0; nf < 5; ++nf) {
            int hb = nf * 16 + hi * 4;
            #pragma unroll
            for (int r = 0; r < 4; ++r) {
                int h = hb + r;
                if (h < NH) out[(size_t)arow * NH + h] = acc[nf][r];
            }
        }
    }
}

// ---------- Fallback: direct per-(edge,h) with atomics (fp32) ----------
__global__ void k_naive(const float* __restrict__ pf, const float* __restrict__ af,
                        const int* __restrict__ atp, const float* __restrict__ W,
                        const float* __restrict__ bias, float* __restrict__ out, int E)
{
    int idx = blockIdx.x * blockDim.x + threadIdx.x;
    if (idx >= E * NH) return;
    int e = idx / NH, h = idx - e * NH;
    int a0 = atp[2 * e], a1 = atp[2 * e + 1];
    float p[NPF];
    #pragma unroll
    for (int f = 0; f < NPF; ++f) p[f] = pf[(size_t)e * NPF + f];
    float acc = 0.f;
    for (int k = 0; k < NH; ++k) {
        float w = bias[h * NH + k];
        #pragma unroll
        for (int f = 0; f < NPF; ++f) w += p[f] * W[f * NW + h * NH + k];
        acc += w * af[a1 * NH + k];
    }
    atomicAdd(&out[a0 * NH + h], acc);
}

extern "C" void kernel_launch(void* const* d_in, const int* in_sizes, int n_in,
                              void* d_out, int out_size, void* d_ws, size_t ws_size,
                              hipStream_t stream) {
    const float* pf   = (const float*)d_in[0];
    const float* af   = (const float*)d_in[1];
    const int*   atp  = (const int*)d_in[2];
    const float* W    = (const float*)d_in[3];
    const float* bias = (const float*)d_in[4];
    float* out = (float*)d_out;
    const int E = in_sizes[2] / 2;

    const size_t offWth = 0;
    const size_t offM   = offWth + (size_t)HP * KK2 * 2;       // 184,320
    const size_t offRs  = offM + (size_t)MR2 * KK2 * 2;        // +23,150,592
    const size_t need   = offRs + (size_t)(NA + 1) * sizeof(int);

    if (ws_size >= need) {
        ushort* wth = (ushort*)((char*)d_ws + offWth);
        ushort* M   = (ushort*)((char*)d_ws + offM);
        int*    rs  = (int*)((char*)d_ws + offRs);

        const int bWt = (HP * (KK2 / 4) + 255) / 256;             // 90
        const int bMz = ((MR2 - NA) * (KK2 / 4) + 255) / 256;     // 54
        const int bR  = (E + 255) / 256;                          // 250
        k_prep<<<bWt + bMz + bR, 256, 0, stream>>>(W, bias, atp, wth, M, rs, E, bWt, bMz);

        k_phaseA<<<NA / 4, 256, 0, stream>>>(af, pf, atp, rs, M);

        k_gemm2<<<MR2 / 16, 64, 0, stream>>>(M, wth, out);
    } else {
        hipMemsetAsync(d_out, 0, (size_t)out_size * sizeof(float), stream);
        k_naive<<<((size_t)E * NH + 255) / 256, 256, 0, stream>>>(pf, af, atp, W, bias, out, E);
    }
}

// Round 9
// 55.835 us; speedup vs baseline: 1.2617x; 1.2617x over previous
//
#include <hip/hip_runtime.h>
#include <stdint.h>

// Problem constants
constexpr int NA  = 10000;   // atoms
constexpr int NH  = 75;      // hidden
constexpr int NPF = 14;      // pair features
constexpr int NW  = 5625;    // 75*75
constexpr int KK  = 1125;    // 15*75 contraction (f=0..13 -> W, f=14 -> bias)
constexpr int KK2 = 1152;    // padded to 36 MFMA k-steps
constexpr int NKC = KK2 / 8; // 144 k-subtiles of 8
constexpr int TB  = NKC * 128;       // 18432 elems per 16-row block ([144][16][8])
constexpr int RBM = 626;             // M row-blocks: 625 real (10000/16) + 1 pad
constexpr int BAT = 2500;            // phase1 atom blocks (4 atoms each)
constexpr int BWT = 90;              // phase1 Wt blocks  (23040 quads)
constexpr int BMZ = 18;              // phase1 M-pad zero blocks (4608 quads)

typedef _Float16 f16;
typedef __attribute__((ext_vector_type(8))) _Float16 f16x8;
typedef __attribute__((ext_vector_type(4))) float floatx4;

__device__ __forceinline__ ushort f2h_bits(float f) {
    return __builtin_bit_cast(ushort, (f16)f);       // v_cvt_f16_f32, RNE
}

// Subtiled layout: elem (row, kk) of a 16-row block lives at
//   blockbase + (kk>>3)*128 + (row&15)*8 + (kk&7)
// so an MFMA fragment (16 rows x 32 k) is 1024 contiguous bytes, lane l at l*16.

// ---------- K1: fused  phaseA (M build) | Wt build | M pad zero ----------
__global__ __launch_bounds__(256) void k_phase1(
    const float* __restrict__ af, const float* __restrict__ pf,
    const int* __restrict__ atp, const float* __restrict__ W,
    const float* __restrict__ bias,
    ushort* __restrict__ Mt, ushort* __restrict__ Wt, int E)
{
    const int b = blockIdx.x, tid = threadIdx.x;
    if (b < BAT) {
        // ---- phase A: M[a][f*75+k] = sum_{e: col0(e)=a} pf[e,f]*af[a1(e),k] ----
        const int wid = tid >> 6, lane = tid & 63;
        const int a = b * 4 + wid;
        // wave-uniform binary search over sorted atp[:,0] for [e0,e1)
        int lo = 0, hi = E;
        while (lo < hi) { int mid = (lo + hi) >> 1; if (atp[2 * mid] < a) lo = mid + 1; else hi = mid; }
        const int e0 = lo;
        hi = E;
        while (lo < hi) { int mid = (lo + hi) >> 1; if (atp[2 * mid] <= a) lo = mid + 1; else hi = mid; }
        const int e1 = lo;

        float mac[15][2] = {};
        for (int e = e0; e < e1; ++e) {
            int a1 = atp[2 * e + 1];
            float av0 = af[a1 * NH + lane];
            float av1 = (lane < 11) ? af[a1 * NH + 64 + lane] : 0.f;
            float p[14];
            #pragma unroll
            for (int f = 0; f < 7; ++f) {
                float2 t = *(const float2*)&pf[(size_t)e * NPF + 2 * f];
                p[2 * f] = t.x; p[2 * f + 1] = t.y;
            }
            #pragma unroll
            for (int f = 0; f < 14; ++f) {
                mac[f][0] += p[f] * av0;
                mac[f][1] += p[f] * av1;
            }
            mac[14][0] += av0;                   // bias slot (pf == 1)
            mac[14][1] += av1;
        }

        ushort* mr = Mt + (size_t)(a >> 4) * TB + (a & 15) * 8;
        #pragma unroll
        for (int f = 0; f < 15; ++f) {
            int kk = f * 75 + lane;
            mr[(kk >> 3) * 128 + (kk & 7)] = f2h_bits(mac[f][0]);
            if (lane < 11) {
                int kk2 = f * 75 + 64 + lane;
                mr[(kk2 >> 3) * 128 + (kk2 & 7)] = f2h_bits(mac[f][1]);
            }
        }
        if (lane < KK2 - KK) {                   // 27 pad cols
            int kk = KK + lane;
            mr[(kk >> 3) * 128 + (kk & 7)] = 0;
        }
    } else if (b < BAT + BWT) {
        // ---- Wt[hb][kc][16][8]: (h, kk) with kk = f*75+k ----
        int idx = (b - BAT) * 256 + tid;         // quad index
        if (idx >= 5 * TB / 4) return;
        int o  = idx * 4;
        int k3 = o & 7;                          // 0 or 4
        int hr = (o >> 3) & 15;
        int t  = o >> 7;
        int kc = t % NKC, hb = t / NKC;
        int h  = hb * 16 + hr;
        ushort4 st = {0, 0, 0, 0};
        if (h < NH) {
            float v[4] = {0.f, 0.f, 0.f, 0.f};
            #pragma unroll
            for (int j = 0; j < 4; ++j) {
                int kk = kc * 8 + k3 + j;
                if (kk < KK) {
                    int f = kk / 75, k = kk - f * 75;
                    v[j] = (f < NPF) ? W[f * NW + h * 75 + k] : bias[h * 75 + k];
                }
            }
            st.x = f2h_bits(v[0]); st.y = f2h_bits(v[1]);
            st.z = f2h_bits(v[2]); st.w = f2h_bits(v[3]);
        }
        ((ushort4*)Wt)[idx] = st;
    } else {
        // ---- zero M pad row-block 625 (rows 10000..10015) ----
        int idx = (b - BAT - BWT) * 256 + tid;
        if (idx < TB / 4) {
            ushort4 z = {0, 0, 0, 0};
            ((ushort4*)(Mt + (size_t)625 * TB))[idx] = z;
        }
    }
}

// ---------- K2: out[a][h] = sum_kk M[a][kk]*Wth[h][kk]  (MFMA, split-K) ----------
// Block = 4 waves over 32 M-rows; wave w does k-steps [9w, 9w+9); LDS reduce.
// All fragment loads are 1024B-contiguous (subtiled layout) -> fully coalesced.
__global__ __launch_bounds__(256) void k_gemm2(
    const ushort* __restrict__ Mt, const ushort* __restrict__ Wt,
    float* __restrict__ out)
{
    __shared__ float red[4][64][42];             // 43008 B, stride 42 -> benign banks

    const int l = threadIdx.x & 63, w = threadIdx.x >> 6;
    const int rb = blockIdx.x * 32;              // rows rb..rb+31 (313 blocks -> 10016)
    const int hi = l >> 4;

    const size_t mb0 = (size_t)(rb >> 4) * TB + l * 8;
    const size_t mb1 = mb0 + TB;

    floatx4 acc[2][5] = {};
    #pragma unroll 3
    for (int s = 0; s < 9; ++s) {
        const int ks = w * 9 + s;
        f16x8 m0 = *(const f16x8*)&Mt[mb0 + ks * 512];
        f16x8 m1 = *(const f16x8*)&Mt[mb1 + ks * 512];
        #pragma unroll
        for (int nf = 0; nf < 5; ++nf) {
            f16x8 wf = *(const f16x8*)&Wt[(size_t)nf * TB + ks * 512 + l * 8];
            acc[0][nf] = __builtin_amdgcn_mfma_f32_16x16x32_f16(wf, m0, acc[0][nf], 0, 0, 0);
            acc[1][nf] = __builtin_amdgcn_mfma_f32_16x16x32_f16(wf, m1, acc[1][nf], 0, 0, 0);
        }
    }

    // stash partials
    #pragma unroll
    for (int m = 0; m < 2; ++m)
        #pragma unroll
        for (int nf = 0; nf < 5; ++nf)
            #pragma unroll
            for (int r = 0; r < 4; ++r)
                red[w][l][m * 20 + nf * 4 + r] = acc[m][nf][r];
    __syncthreads();

    // wave w reduces j in [10w, 10w+10) across the 4 k-partials and stores
    #pragma unroll
    for (int jj = 0; jj < 10; ++jj) {
        int j = w * 10 + jj;
        float s = red[0][l][j] + red[1][l][j] + red[2][l][j] + red[3][l][j];
        int m   = j / 20;
        int rem = j - m * 20;
        int nf  = rem >> 2, r = rem & 3;
        int row = rb + m * 16 + (l & 15);
        int h   = nf * 16 + hi * 4 + r;
        if (row < NA && h < NH)
            out[(size_t)row * NH + h] = s;
    }
}

// ---------- Fallback: direct per-(edge,h) with atomics (fp32) ----------
__global__ void k_naive(const float* __restrict__ pf, const float* __restrict__ af,
                        const int* __restrict__ atp, const float* __restrict__ W,
                        const float* __restrict__ bias, float* __restrict__ out, int E)
{
    int idx = blockIdx.x * blockDim.x + threadIdx.x;
    if (idx >= E * NH) return;
    int e = idx / NH, h = idx - e * NH;
    int a0 = atp[2 * e], a1 = atp[2 * e + 1];
    float p[NPF];
    #pragma unroll
    for (int f = 0; f < NPF; ++f) p[f] = pf[(size_t)e * NPF + f];
    float acc = 0.f;
    for (int k = 0; k < NH; ++k) {
        float w = bias[h * NH + k];
        #pragma unroll
        for (int f = 0; f < NPF; ++f) w += p[f] * W[f * NW + h * NH + k];
        acc += w * af[a1 * NH + k];
    }
    atomicAdd(&out[a0 * NH + h], acc);
}

extern "C" void kernel_launch(void* const* d_in, const int* in_sizes, int n_in,
                              void* d_out, int out_size, void* d_ws, size_t ws_size,
                              hipStream_t stream) {
    const float* pf   = (const float*)d_in[0];
    const float* af   = (const float*)d_in[1];
    const int*   atp  = (const int*)d_in[2];
    const float* W    = (const float*)d_in[3];
    const float* bias = (const float*)d_in[4];
    float* out = (float*)d_out;
    const int E = in_sizes[2] / 2;

    const size_t offWt = 0;
    const size_t offMt = offWt + (size_t)5 * TB * 2;           // 184,320
    const size_t need  = offMt + (size_t)RBM * TB * 2;         // +23,076,864

    if (ws_size >= need) {
        ushort* Wt = (ushort*)((char*)d_ws + offWt);
        ushort* Mt = (ushort*)((char*)d_ws + offMt);

        k_phase1<<<BAT + BWT + BMZ, 256, 0, stream>>>(af, pf, atp, W, bias, Mt, Wt, E);
        k_gemm2<<<313, 256, 0, stream>>>(Mt, Wt, out);         // 313*32 = 10016 rows
    } else {
        hipMemsetAsync(d_out, 0, (size_t)out_size * sizeof(float), stream);
        k_naive<<<((size_t)E * NH + 255) / 256, 256, 0, stream>>>(pf, af, atp, W, bias, out, E);
    }
}

// Round 10
// 46.276 us; speedup vs baseline: 1.5223x; 1.2066x over previous
//
#include <hip/hip_runtime.h>
#include <stdint.h>

// Problem constants
constexpr int NA  = 10000;   // atoms
constexpr int NH  = 75;      // hidden
constexpr int NPF = 14;      // pair features
constexpr int NW  = 5625;    // 75*75
constexpr int KK  = 1125;    // 15*75 contraction (f=0..13 -> W, f=14 -> bias)
constexpr int KK2 = 1152;    // padded to 36 MFMA k-steps
constexpr int NKC = KK2 / 8; // 144 k-subtiles of 8
constexpr int TB  = NKC * 128;       // 18432 elems per 16-row block ([144][16][8])
constexpr int RBM = 626;             // M row-blocks: 625 real (10000/16) + 1 pad
constexpr int BWT = 90;              // Wt build blocks (23040 quads)
constexpr int BMZ = 18;              // M-pad zero blocks (4608 quads)

typedef _Float16 f16;
typedef __attribute__((ext_vector_type(8))) _Float16 f16x8;
typedef __attribute__((ext_vector_type(4))) float floatx4;

__device__ __forceinline__ ushort f2h_bits(float f) {
    return __builtin_bit_cast(ushort, (f16)f);       // v_cvt_f16_f32, RNE
}

// Subtiled layout: elem (row, kk) of a 16-row block lives at
//   blockbase + (kk>>3)*128 + (row&15)*8 + (kk&7)
// so an MFMA fragment (16 rows x 32 k) is 1024 contiguous bytes, lane l at l*16.

// ---------- K1: prep = rowstart CSR | Wt build | M pad zero ----------
__global__ __launch_bounds__(256) void k_prep(
    const int* __restrict__ atp, const float* __restrict__ W,
    const float* __restrict__ bias,
    ushort* __restrict__ Wt, ushort* __restrict__ Mt, int* __restrict__ rs,
    int E, int bR)
{
    const int b = blockIdx.x, tid = threadIdx.x;
    if (b < bR) {
        // rowstart CSR from sorted atom_to_pair[:,0]
        int e = b * 256 + tid;
        if (e >= E) return;
        int c  = atp[2 * e];
        int cp = (e == 0) ? -1 : atp[2 * (e - 1)];
        for (int a = cp + 1; a <= c; ++a) rs[a] = e;
        if (e == E - 1)
            for (int a = c + 1; a <= NA; ++a) rs[a] = E;
    } else if (b < bR + BWT) {
        // Wt[hb][kc][16][8]: (h, kk) with kk = f*75+k
        int idx = (b - bR) * 256 + tid;          // quad index
        if (idx >= 5 * TB / 4) return;
        int o  = idx * 4;
        int k3 = o & 7;                          // 0 or 4
        int hr = (o >> 3) & 15;
        int t  = o >> 7;
        int kc = t % NKC, hb = t / NKC;
        int h  = hb * 16 + hr;
        ushort4 st = {0, 0, 0, 0};
        if (h < NH) {
            float v[4] = {0.f, 0.f, 0.f, 0.f};
            #pragma unroll
            for (int j = 0; j < 4; ++j) {
                int kk = kc * 8 + k3 + j;
                if (kk < KK) {
                    int f = kk / 75, k = kk - f * 75;
                    v[j] = (f < NPF) ? W[f * NW + h * 75 + k] : bias[h * 75 + k];
                }
            }
            st.x = f2h_bits(v[0]); st.y = f2h_bits(v[1]);
            st.z = f2h_bits(v[2]); st.w = f2h_bits(v[3]);
        }
        ((ushort4*)Wt)[idx] = st;
    } else {
        // zero M pad row-block 625 (rows 10000..10015)
        int idx = (b - bR - BWT) * 256 + tid;
        if (idx < TB / 4) {
            ushort4 z = {0, 0, 0, 0};
            ((ushort4*)(Mt + (size_t)625 * TB))[idx] = z;
        }
    }
}

// ---------- K2: phase A — M[a][f*75+k] = sum_{e in a} pf[e,f]*af[a1(e),k] ----------
// One wave per atom. a1s bulk-loaded 64 at a time (one coalesced load), then
// broadcast per-iteration via shfl -> af/pf loads are independent, pipelineable.
__global__ __launch_bounds__(256, 1) void k_phaseA(
    const float* __restrict__ af, const float* __restrict__ pf,
    const int* __restrict__ atp, const int* __restrict__ rs,
    ushort* __restrict__ Mt)
{
    const int wid = threadIdx.x >> 6, lane = threadIdx.x & 63;
    const int a = blockIdx.x * 4 + wid;          // 2500*4 = 10000 exactly
    const int e0 = rs[a], e1 = rs[a + 1];

    float mac0[15] = {}, mac1[15] = {};
    for (int base = e0; base < e1; base += 64) {
        int n = e1 - base; if (n > 64) n = 64;
        int my = (lane < n) ? atp[2 * (base + lane) + 1] : 0;
        for (int i = 0; i < n; ++i) {
            int a1 = __shfl(my, i);
            float av0 = af[a1 * NH + lane];
            float av1 = (lane < 11) ? af[a1 * NH + 64 + lane] : 0.f;
            const float* pfe = pf + (size_t)(base + i) * NPF;
            float p[14];
            #pragma unroll
            for (int f = 0; f < 7; ++f) {
                float2 t = *(const float2*)&pfe[2 * f];
                p[2 * f] = t.x; p[2 * f + 1] = t.y;
            }
            #pragma unroll
            for (int f = 0; f < 14; ++f) {
                mac0[f] += p[f] * av0;
                mac1[f] += p[f] * av1;
            }
            mac0[14] += av0;                     // bias slot (pf == 1)
            mac1[14] += av1;
        }
    }

    ushort* mr = Mt + (size_t)(a >> 4) * TB + (a & 15) * 8;
    #pragma unroll
    for (int f = 0; f < 15; ++f) {
        int kk = f * 75 + lane;
        mr[(kk >> 3) * 128 + (kk & 7)] = f2h_bits(mac0[f]);
        if (lane < 11) {
            int kk2 = f * 75 + 64 + lane;
            mr[(kk2 >> 3) * 128 + (kk2 & 7)] = f2h_bits(mac1[f]);
        }
    }
    if (lane < KK2 - KK) {                       // 27 pad cols
        int kk = KK + lane;
        mr[(kk >> 3) * 128 + (kk & 7)] = 0;
    }
}

// ---------- K3: out[a][h] = sum_kk M[a][kk]*Wt[h][kk]  (MFMA, split-K) ----------
// Block = 4 waves over 32 M-rows; wave w does k-steps [9w, 9w+9); LDS reduce.
// All fragment loads are 1024B-contiguous (subtiled layout) -> fully coalesced.
__global__ __launch_bounds__(256) void k_gemm2(
    const ushort* __restrict__ Mt, const ushort* __restrict__ Wt,
    float* __restrict__ out)
{
    __shared__ float red[4][64][42];             // 43008 B, stride 42 -> benign banks

    const int l = threadIdx.x & 63, w = threadIdx.x >> 6;
    const int rb = blockIdx.x * 32;              // rows rb..rb+31 (313 blocks -> 10016)
    const int hi = l >> 4;

    const size_t mb0 = (size_t)(rb >> 4) * TB + l * 8;
    const size_t mb1 = mb0 + TB;

    floatx4 acc[2][5] = {};
    #pragma unroll 3
    for (int s = 0; s < 9; ++s) {
        const int ks = w * 9 + s;
        f16x8 m0 = *(const f16x8*)&Mt[mb0 + ks * 512];
        f16x8 m1 = *(const f16x8*)&Mt[mb1 + ks * 512];
        #pragma unroll
        for (int nf = 0; nf < 5; ++nf) {
            f16x8 wf = *(const f16x8*)&Wt[(size_t)nf * TB + ks * 512 + l * 8];
            acc[0][nf] = __builtin_amdgcn_mfma_f32_16x16x32_f16(wf, m0, acc[0][nf], 0, 0, 0);
            acc[1][nf] = __builtin_amdgcn_mfma_f32_16x16x32_f16(wf, m1, acc[1][nf], 0, 0, 0);
        }
    }

    // stash partials
    #pragma unroll
    for (int m = 0; m < 2; ++m)
        #pragma unroll
        for (int nf = 0; nf < 5; ++nf)
            #pragma unroll
            for (int r = 0; r < 4; ++r)
                red[w][l][m * 20 + nf * 4 + r] = acc[m][nf][r];
    __syncthreads();

    // wave w reduces j in [10w, 10w+10) across the 4 k-partials and stores
    #pragma unroll
    for (int jj = 0; jj < 10; ++jj) {
        int j = w * 10 + jj;
        float s = red[0][l][j] + red[1][l][j] + red[2][l][j] + red[3][l][j];
        int m   = j / 20;
        int rem = j - m * 20;
        int nf  = rem >> 2, r = rem & 3;
        int row = rb + m * 16 + (l & 15);
        int h   = nf * 16 + hi * 4 + r;
        if (row < NA && h < NH)
            out[(size_t)row * NH + h] = s;
    }
}

// ---------- Fallback: direct per-(edge,h) with atomics (fp32) ----------
__global__ void k_naive(const float* __restrict__ pf, const float* __restrict__ af,
                        const int* __restrict__ atp, const float* __restrict__ W,
                        const float* __restrict__ bias, float* __restrict__ out, int E)
{
    int idx = blockIdx.x * blockDim.x + threadIdx.x;
    if (idx >= E * NH) return;
    int e = idx / NH, h = idx - e * NH;
    int a0 = atp[2 * e], a1 = atp[2 * e + 1];
    float p[NPF];
    #pragma unroll
    for (int f = 0; f < NPF; ++f) p[f] = pf[(size_t)e * NPF + f];
    float acc = 0.f;
    for (int k = 0; k < NH; ++k) {
        float w = bias[h * NH + k];
        #pragma unroll
        for (int f = 0; f < NPF; ++f) w += p[f] * W[f * NW + h * NH + k];
        acc += w * af[a1 * NH + k];
    }
    atomicAdd(&out[a0 * NH + h], acc);
}

extern "C" void kernel_launch(void* const* d_in, const int* in_sizes, int n_in,
                              void* d_out, int out_size, void* d_ws, size_t ws_size,
                              hipStream_t stream) {
    const float* pf   = (const float*)d_in[0];
    const float* af   = (const float*)d_in[1];
    const int*   atp  = (const int*)d_in[2];
    const float* W    = (const float*)d_in[3];
    const float* bias = (const float*)d_in[4];
    float* out = (float*)d_out;
    const int E = in_sizes[2] / 2;

    const size_t offWt = 0;
    const size_t offMt = offWt + (size_t)5 * TB * 2;           // 184,320
    const size_t offRs = offMt + (size_t)RBM * TB * 2;         // +23,076,864
    const size_t need  = offRs + (size_t)(NA + 1) * sizeof(int);

    if (ws_size >= need) {
        ushort* Wt = (ushort*)((char*)d_ws + offWt);
        ushort* Mt = (ushort*)((char*)d_ws + offMt);
        int*    rs = (int*)((char*)d_ws + offRs);

        const int bR = (E + 255) / 256;                        // 250
        k_prep<<<bR + BWT + BMZ, 256, 0, stream>>>(atp, W, bias, Wt, Mt, rs, E, bR);
        k_phaseA<<<NA / 4, 256, 0, stream>>>(af, pf, atp, rs, Mt);
        k_gemm2<<<313, 256, 0, stream>>>(Mt, Wt, out);         // 313*32 = 10016 rows
    } else {
        hipMemsetAsync(d_out, 0, (size_t)out_size * sizeof(float), stream);
        k_naive<<<((size_t)E * NH + 255) / 256, 256, 0, stream>>>(pf, af, atp, W, bias, out, E);
    }
}